// Round 6
// baseline (294.830 us; speedup 1.0000x reference)
//
#include <hip/hip_runtime.h>

// SNN: x[B,T,D] -> GEMM1 -> LIF -> GEMM2 -> LIF -> (last t) -> FC -> out[B,O]
// B=32, T=1024, D=H=512, O=256. All intermediates in natural [B,T,H] order.
//
// Both GEMMs run on bf16 MFMA via exact-ish splits:
//   GEMM2: spikes are {0,1} (bf16-exact); W1 = w1h + w1l  -> 2 MFMAs/acc.
//   GEMM1: x = xh + xl, W0 = w0h + w0l; full 4-term product
//          xh.wh + xh.wl + xl.wh + xl.wl  (4 MFMAs/acc; all operands already
//          in LDS, so the 4th term costs only the MFMA issue). Residual =
//          split representation error ~2^-19 rel ~ below fp32 reorder noise.
// Fallback: if ws_size can't hold the x-split buffers, GEMM1 runs fp32 VALU.
// All bf16 as ushort bit patterns; fragments are ext_vector_type(8) short.

#define DECAY 0.9f
#define THRESH 1.0f

constexpr int Bsz = 32;
constexpr int Tsz = 1024;
constexpr int Dsz = 512;
constexpr int Hsz = 512;
constexpr int Osz = 256;

using s16x8 = __attribute__((ext_vector_type(8))) short;
using f32x4 = __attribute__((ext_vector_type(4))) float;

// ---------------------------------------------------------------------------
// bf16 bit-pattern helpers (RNE)
// ---------------------------------------------------------------------------
__device__ __forceinline__ unsigned short f2bf_rne(float x) {
  unsigned b = __float_as_uint(x);
  return (unsigned short)((b + 0x7FFFu + ((b >> 16) & 1u)) >> 16);
}
__device__ __forceinline__ float bf2f(unsigned short h) {
  return __uint_as_float(((unsigned)h) << 16);
}

// Split BOTH weight matrices (each n fp32) into hi/lo bf16 patterns.
__global__ __launch_bounds__(256)
void wsplit2(const float* __restrict__ W0, unsigned short* __restrict__ h0,
             unsigned short* __restrict__ l0, const float* __restrict__ W1,
             unsigned short* __restrict__ h1, unsigned short* __restrict__ l1,
             int n) {
  const int i = blockIdx.x * 256 + threadIdx.x;
  if (i < n) {
    float w = W0[i];
    unsigned short h = f2bf_rne(w);
    h0[i] = h;
    l0[i] = f2bf_rne(w - bf2f(h));
    w = W1[i];
    h = f2bf_rne(w);
    h1[i] = h;
    l1[i] = f2bf_rne(w - bf2f(h));
  }
}

// Split x (n4 float4s) into hi/lo bf16 patterns, vectorized, grid-stride.
__global__ __launch_bounds__(256)
void xsplit(const float* __restrict__ x, unsigned short* __restrict__ xh,
            unsigned short* __restrict__ xl, int n4) {
  int i = blockIdx.x * 256 + threadIdx.x;
  const int stride = gridDim.x * 256;
  for (; i < n4; i += stride) {
    const float4 v = ((const float4*)x)[i];
    ushort4 hh, ll;
    hh.x = f2bf_rne(v.x); ll.x = f2bf_rne(v.x - bf2f(hh.x));
    hh.y = f2bf_rne(v.y); ll.y = f2bf_rne(v.y - bf2f(hh.y));
    hh.z = f2bf_rne(v.z); ll.z = f2bf_rne(v.z - bf2f(hh.z));
    hh.w = f2bf_rne(v.w); ll.w = f2bf_rne(v.w - bf2f(hh.w));
    ((ushort4*)xh)[i] = hh;
    ((ushort4*)xl)[i] = ll;
  }
}

// ---------------------------------------------------------------------------
// global -> LDS direct load, 16B/lane. LDS dest = wave-uniform base (HW adds
// lane*16). AS casts via integer roundtrip (CK amd_direct_load pattern; LDS
// generic addr low 32 bits == LDS offset).
// ---------------------------------------------------------------------------
typedef __attribute__((address_space(3))) unsigned int lds_u32;
typedef __attribute__((address_space(1))) unsigned int glb_u32;

__device__ __forceinline__ void gload_lds16(const void* g, void* l) {
  __builtin_amdgcn_global_load_lds(
      (glb_u32*)(unsigned long long)g,
      (lds_u32*)(unsigned int)(unsigned long long)l, 16, 0, 0);
}

// ---------------------------------------------------------------------------
// Unified MFMA GEMM (NT): C[r,n] = bias[n] + sum_k A(r,k)*W(n,k), K=N=512.
// NAT=1: A = A0 (spikes);   acc += A0.Bh + A0.Bl                    (2 MFMA)
// NAT=2: A = A0+A1 (xh,xl); acc += A0.Bh + A0.Bl + A1.Bh + A1.Bl   (4 MFMA)
// 128x128 tile, BK=32, 4 waves (2x2 of 64x64), 16x16x32 MFMA, 4x4 frags/wave,
// global_load_lds width-16 staging, 2-barrier K-loop (m97 structure).
// ---------------------------------------------------------------------------
template <int NAT>
__global__ __launch_bounds__(256)
void gemm_mfma(const unsigned short* __restrict__ A0,
               const unsigned short* __restrict__ A1,
               const unsigned short* __restrict__ Bhp,
               const unsigned short* __restrict__ Blp,
               const float* __restrict__ bias, float* __restrict__ C, int M) {
  constexpr int K = 512, N = 512;
  constexpr int NB = NAT + 2;               // LDS buffers
  __shared__ s16x8 sm[NB * 512];            // each buf: 128 rows x 32 bf16

  const int tid  = threadIdx.x;
  const int w    = tid >> 6;
  const int lane = tid & 63;
  const int wr   = w >> 1;     // wave row 0..1 (64 rows)
  const int wc   = w & 1;      // wave col 0..1
  const int frow = lane & 15;  // fragment row/col within 16x16
  const int kgrp = lane >> 4;  // k-group 0..3 (8 bf16 each)

  const int mtile = blockIdx.x * 128;
  const int ntile = blockIdx.y * 128;

  const unsigned short* srcs[NB];
  srcs[0] = A0;
  if (NAT == 2) srcs[1] = A1;
  srcs[NAT]     = Bhp;
  srcs[NAT + 1] = Blp;

  f32x4 acc[4][4];
#pragma unroll
  for (int i = 0; i < 4; ++i)
#pragma unroll
    for (int j = 0; j < 4; ++j) acc[i][j] = (f32x4){0.f, 0.f, 0.f, 0.f};

  for (int kt = 0; kt < K / 32; ++kt) {
    const int kbase = kt * 32;
    __syncthreads();  // previous fragment reads complete before overwrite
#pragma unroll
    for (int r = 0; r < 2; ++r) {
      const int chunk = r * 4 + w;          // 0..7, wave-uniform
      const int li    = chunk * 64 + lane;  // 16B unit 0..511
      const int row   = li >> 2;            // tile row 0..127
      const int ch    = li & 3;             // 8-col group
      const int coff  = kbase + ch * 8;
#pragma unroll
      for (int buf = 0; buf < NB; ++buf) {
        const int rbase = (buf < NAT) ? mtile : ntile;
        gload_lds16(srcs[buf] + (size_t)(rbase + row) * K + coff,
                    &sm[buf * 512 + chunk * 64]);
      }
    }
    __syncthreads();  // vmcnt(0) drain -> LDS writes visible

    s16x8 a0f[4], a1f[4], bhf[4], blf[4];
#pragma unroll
    for (int mi = 0; mi < 4; ++mi) {
      const int off = (wr * 64 + mi * 16 + frow) * 4 + kgrp;
      a0f[mi] = sm[off];
      if (NAT == 2) a1f[mi] = sm[512 + off];
    }
#pragma unroll
    for (int nj = 0; nj < 4; ++nj) {
      const int off = (wc * 64 + nj * 16 + frow) * 4 + kgrp;
      bhf[nj] = sm[NAT * 512 + off];
      blf[nj] = sm[(NAT + 1) * 512 + off];
    }
#pragma unroll
    for (int mi = 0; mi < 4; ++mi)
#pragma unroll
      for (int nj = 0; nj < 4; ++nj) {
        acc[mi][nj] = __builtin_amdgcn_mfma_f32_16x16x32_bf16(
            a0f[mi], bhf[nj], acc[mi][nj], 0, 0, 0);
        acc[mi][nj] = __builtin_amdgcn_mfma_f32_16x16x32_bf16(
            a0f[mi], blf[nj], acc[mi][nj], 0, 0, 0);
        if (NAT == 2) {
          acc[mi][nj] = __builtin_amdgcn_mfma_f32_16x16x32_bf16(
              a1f[mi], bhf[nj], acc[mi][nj], 0, 0, 0);
          acc[mi][nj] = __builtin_amdgcn_mfma_f32_16x16x32_bf16(
              a1f[mi], blf[nj], acc[mi][nj], 0, 0, 0);
        }
      }
  }

  // epilogue: C/D layout col=lane&15, row=(lane>>4)*4+reg  [m89/m91]
#pragma unroll
  for (int nj = 0; nj < 4; ++nj) {
    const int col = ntile + wc * 64 + nj * 16 + frow;
    const float b = bias[col];
#pragma unroll
    for (int mi = 0; mi < 4; ++mi) {
#pragma unroll
      for (int ri = 0; ri < 4; ++ri) {
        const int row = mtile + wr * 64 + mi * 16 + kgrp * 4 + ri;
        C[(size_t)row * N + col] = acc[mi][nj][ri] + b;
      }
    }
  }
}

// ---------------------------------------------------------------------------
// Fallback GEMM1 (NT, fp32 vector), natural row order. 128x128x16, 256 thr,
// 8x8 micro, XOR-swizzled LDS chunks.
// ---------------------------------------------------------------------------
__global__ __launch_bounds__(256)
void gemm_nt(const float* __restrict__ A, const float* __restrict__ W,
             const float* __restrict__ bias, float* __restrict__ C,
             int M, int N, int K) {
  __shared__ float4 As[128 * 4];
  __shared__ float4 Bs[128 * 4];

  const int tid  = threadIdx.x;
  const int w    = tid >> 6;
  const int lane = tid & 63;
  const int m0 = (w >> 1) * 64 + (lane >> 3) * 8;
  const int n0 = (w & 1)  * 64 + (lane & 7) * 8;

  const int mtile = blockIdx.x * 128;
  const int ntile = blockIdx.y * 128;

  const int sr  = tid >> 1;
  const int sc  = (tid & 1) * 2;
  const int swz = (sr >> 3) & 3;

  const float4* ag = (const float4*)(A + (size_t)(mtile + sr) * K);
  const float4* bg = (const float4*)(W + (size_t)(ntile + sr) * K);

  float acc[8][8];
#pragma unroll
  for (int i = 0; i < 8; ++i)
#pragma unroll
    for (int j = 0; j < 8; ++j) acc[i][j] = 0.f;

  for (int k0 = 0; k0 < K; k0 += 16) {
    const int kc4 = k0 >> 2;
    float4 av0 = ag[kc4 + sc], av1 = ag[kc4 + sc + 1];
    float4 bv0 = bg[kc4 + sc], bv1 = bg[kc4 + sc + 1];
    __syncthreads();
    As[sr * 4 + (sc ^ swz)] = av0;  As[sr * 4 + ((sc + 1) ^ swz)] = av1;
    Bs[sr * 4 + (sc ^ swz)] = bv0;  Bs[sr * 4 + ((sc + 1) ^ swz)] = bv1;
    __syncthreads();

#pragma unroll
    for (int kc = 0; kc < 4; ++kc) {
      float4 a4[8], b4[8];
#pragma unroll
      for (int i = 0; i < 8; ++i) {
        const int m = m0 + i;
        a4[i] = As[m * 4 + (kc ^ ((m >> 3) & 3))];
        const int n = n0 + i;
        b4[i] = Bs[n * 4 + (kc ^ ((n >> 3) & 3))];
      }
#pragma unroll
      for (int i = 0; i < 8; ++i)
#pragma unroll
        for (int j = 0; j < 8; ++j) {
          acc[i][j] += a4[i].x * b4[j].x;
          acc[i][j] += a4[i].y * b4[j].y;
          acc[i][j] += a4[i].z * b4[j].z;
          acc[i][j] += a4[i].w * b4[j].w;
        }
    }
  }

  float bb[8];
#pragma unroll
  for (int j = 0; j < 8; ++j) bb[j] = bias[ntile + n0 + j];
#pragma unroll
  for (int i = 0; i < 8; ++i) {
    float* cp = C + (size_t)(mtile + m0 + i) * N + ntile + n0;
    float4 o0, o1;
    o0.x = acc[i][0] + bb[0]; o0.y = acc[i][1] + bb[1];
    o0.z = acc[i][2] + bb[2]; o0.w = acc[i][3] + bb[3];
    o1.x = acc[i][4] + bb[4]; o1.y = acc[i][5] + bb[5];
    o1.z = acc[i][6] + bb[6]; o1.w = acc[i][7] + bb[7];
    ((float4*)cp)[0] = o0;
    ((float4*)cp)[1] = o1;
  }
}

// ---------------------------------------------------------------------------
// LIF scan over T on [B,T,H] currents. Chain (b,h): stride H per step.
// Wave = 64 consecutive h -> 256B contiguous per timestep (coalesced).
// 32-deep prefetch ring (~2MB in flight chip-wide ~ BW*latency product)
// hides HBM latency at the fixed 16384-chain parallelism.
// ---------------------------------------------------------------------------
constexpr int PF = 32;  // divides Tsz

__global__ __launch_bounds__(64)
void lif_spikes_bf16(const float* __restrict__ iin,
                     unsigned short* __restrict__ sout) {
  const int idx = blockIdx.x * 64 + threadIdx.x;  // 0..B*H-1
  const int b = idx >> 9, h = idx & 511;
  const float* p = iin + (size_t)b * Tsz * Hsz + h;
  unsigned short* q = sout + (size_t)b * Tsz * Hsz + h;

  float buf[PF];
#pragma unroll
  for (int j = 0; j < PF; ++j) buf[j] = p[(size_t)j * Hsz];

  float u = 0.f, s = 0.f;
  int t = 0;
  for (; t < Tsz - PF; t += PF) {
#pragma unroll
    for (int j = 0; j < PF; ++j) {
      const float cur = buf[j];
      buf[j] = p[(size_t)(t + PF + j) * Hsz];  // prefetch next block
      u = DECAY * (u - s * THRESH) + cur;
      s = (u > THRESH) ? 1.f : 0.f;
      q[(size_t)(t + j) * Hsz] =
          (u > THRESH) ? (unsigned short)0x3F80 : (unsigned short)0;
    }
  }
#pragma unroll
  for (int j = 0; j < PF; ++j) {
    const float cur = buf[j];
    u = DECAY * (u - s * THRESH) + cur;
    s = (u > THRESH) ? 1.f : 0.f;
    q[(size_t)(t + j) * Hsz] =
        (u > THRESH) ? (unsigned short)0x3F80 : (unsigned short)0;
  }
}

__global__ __launch_bounds__(64)
void lif_last_f32(const float* __restrict__ iin, float* __restrict__ sout) {
  const int idx = blockIdx.x * 64 + threadIdx.x;
  const int b = idx >> 9, h = idx & 511;
  const float* p = iin + (size_t)b * Tsz * Hsz + h;

  float buf[PF];
#pragma unroll
  for (int j = 0; j < PF; ++j) buf[j] = p[(size_t)j * Hsz];

  float u = 0.f, s = 0.f;
  int t = 0;
  for (; t < Tsz - PF; t += PF) {
#pragma unroll
    for (int j = 0; j < PF; ++j) {
      const float cur = buf[j];
      buf[j] = p[(size_t)(t + PF + j) * Hsz];
      u = DECAY * (u - s * THRESH) + cur;
      s = (u > THRESH) ? 1.f : 0.f;
    }
  }
#pragma unroll
  for (int j = 0; j < PF; ++j) {
    const float cur = buf[j];
    u = DECAY * (u - s * THRESH) + cur;
    s = (u > THRESH) ? 1.f : 0.f;
  }
  sout[idx] = s;  // sl[b*H + h]
}

// ---------------------------------------------------------------------------
// FC: out[b,o] = fc_b[o] + sum_h sl[b,h] * fcW[o,h].
// ---------------------------------------------------------------------------
__global__ __launch_bounds__(256)
void fc_kernel(const float* __restrict__ sl, const float* __restrict__ fcW,
               const float* __restrict__ fcb, float* __restrict__ out) {
  const int b = blockIdx.x;
  const int o = threadIdx.x;
  const float4* wv = (const float4*)(fcW + (size_t)o * Hsz);
  const float4* sv = (const float4*)(sl + (size_t)b * Hsz);
  float acc = 0.f;
#pragma unroll 4
  for (int k = 0; k < Hsz / 4; ++k) {
    const float4 a = sv[k];
    const float4 ww = wv[k];
    acc += a.x * ww.x + a.y * ww.y + a.z * ww.z + a.w * ww.w;
  }
  out[(size_t)b * Osz + o] = acc + fcb[o];
}

// ---------------------------------------------------------------------------
extern "C" void kernel_launch(void* const* d_in, const int* in_sizes, int n_in,
                              void* d_out, int out_size, void* d_ws,
                              size_t ws_size, hipStream_t stream) {
  const float* x   = (const float*)d_in[0];  // [B,T,D]
  const float* W0  = (const float*)d_in[1];  // [H,D]
  const float* b0  = (const float*)d_in[2];  // [H]
  const float* W1  = (const float*)d_in[3];  // [H,H]
  const float* b1  = (const float*)d_in[4];  // [H]
  const float* fcW = (const float*)d_in[5];  // [O,H]
  const float* fcb = (const float*)d_in[6];  // [O]
  float* out = (float*)d_out;                // [B,O]

  constexpr size_t ELEMS = (size_t)Bsz * Tsz * Hsz;  // 16.7M (= B*T*D too)
  constexpr size_t WSZ   = (size_t)Hsz * Dsz;        // 262144

  // Layout: i0 | s0(=xh) | w1h | w1l | sl | xl | w0h | w0l
  float*          ws   = (float*)d_ws;
  float*          i0   = ws;                               // 64MB, reused as i1
  unsigned short* us0  = (unsigned short*)(ws + ELEMS);    // xh then s0, 32MB
  unsigned short* w1h  = us0 + ELEMS;
  unsigned short* w1l  = w1h + WSZ;
  float*          sl   = (float*)(w1l + WSZ);              // [B,H]
  unsigned short* uxl  = (unsigned short*)(sl + (size_t)Bsz * Hsz);  // 32MB
  unsigned short* w0h  = uxl + ELEMS;
  unsigned short* w0l  = w0h + WSZ;
  float*          i1   = i0;

  const size_t need_full =
      (char*)(w0l + WSZ) - (char*)d_ws;  // ~130MB
  const bool mfma1 = ws_size >= need_full;

  const int M = Bsz * Tsz;  // 32768
  dim3 gtile(M / 128, Hsz / 128);

  if (mfma1) {
    // Both weight splits in one launch (every call; no static state)
    wsplit2<<<(int)(WSZ / 256), 256, 0, stream>>>(W0, w0h, w0l, W1, w1h, w1l,
                                                  (int)WSZ);
    xsplit<<<2048, 256, 0, stream>>>(x, us0 /*xh*/, uxl, (int)(ELEMS / 4));
    // GEMM1 (MFMA 4-term): i0[r,h] = x[r,:].W0[h,:] + b0[h]
    gemm_mfma<2><<<gtile, 256, 0, stream>>>(us0, uxl, w0h, w0l, b0, i0, M);
  } else {
    wsplit2<<<(int)(WSZ / 256), 256, 0, stream>>>(W1, w1h, w1l, W1, w1h, w1l,
                                                  (int)WSZ);
    // Fallback: fp32 vector GEMM1
    gemm_nt<<<gtile, 256, 0, stream>>>(x, W0, b0, i0, M, Hsz, Dsz);
  }

  // LIF1: bf16 spike patterns for all t (overwrites xh region)
  lif_spikes_bf16<<<(Bsz * Hsz) / 64, 64, 0, stream>>>(i0, us0);

  // GEMM2 (MFMA 2-term): i1[r,g] = s0[r,:].W1[g,:] + b1[g]
  gemm_mfma<1><<<gtile, 256, 0, stream>>>(us0, nullptr, w1h, w1l, b1, i1, M);

  // LIF2: only final-timestep spikes
  lif_last_f32<<<(Bsz * Hsz) / 64, 64, 0, stream>>>(i1, sl);

  // FC
  fc_kernel<<<Bsz, Osz, 0, stream>>>(sl, fcW, fcb, out);
}

// Round 8
// 287.207 us; speedup vs baseline: 1.0265x; 1.0265x over previous
//
#include <hip/hip_runtime.h>

// SNN: x[B,T,D] -> GEMM1 -> LIF -> GEMM2 -> LIF -> (last t) -> FC -> out[B,O]
// B=32, T=1024, D=H=512, O=256. All intermediates in natural [B,T,H] order.
//
// Both GEMMs run on bf16 MFMA via exact splits (R6: PASS, absmax 0.0):
//   GEMM2: spikes are {0,1} (bf16-exact); W1 = w1h + w1l  -> 2 MFMAs/acc.
//   GEMM1: x = xh + xl, W0 = w0h + w0l; full 4-term product -> 4 MFMAs/acc.
// R7 changes (unbenched - R7 round timed out; resubmitted for A/B vs R6):
//   - LIF prefetch ring PF 32 -> 64 (4MB in flight chip-wide; LIF was
//     latency-bound at ~2-3 TB/s with 1 wave/CU; ~145us combined).
//   - GEMM LDS chunk permutation c = kgrp ^ ((row>>1)&3): fragment
//     ds_read_b128 was 8-way bank-aliased (4.19M conflicts/dispatch).
//     Permutation applied to per-lane GLOBAL source addr (LDS stays linear,
//     global_load_lds constraint) and to the fragment read index.

#define DECAY 0.9f
#define THRESH 1.0f

constexpr int Bsz = 32;
constexpr int Tsz = 1024;
constexpr int Dsz = 512;
constexpr int Hsz = 512;
constexpr int Osz = 256;

using s16x8 = __attribute__((ext_vector_type(8))) short;
using f32x4 = __attribute__((ext_vector_type(4))) float;

// ---------------------------------------------------------------------------
// bf16 bit-pattern helpers (RNE)
// ---------------------------------------------------------------------------
__device__ __forceinline__ unsigned short f2bf_rne(float x) {
  unsigned b = __float_as_uint(x);
  return (unsigned short)((b + 0x7FFFu + ((b >> 16) & 1u)) >> 16);
}
__device__ __forceinline__ float bf2f(unsigned short h) {
  return __uint_as_float(((unsigned)h) << 16);
}

// Split BOTH weight matrices (each n fp32) into hi/lo bf16 patterns.
__global__ __launch_bounds__(256)
void wsplit2(const float* __restrict__ W0, unsigned short* __restrict__ h0,
             unsigned short* __restrict__ l0, const float* __restrict__ W1,
             unsigned short* __restrict__ h1, unsigned short* __restrict__ l1,
             int n) {
  const int i = blockIdx.x * 256 + threadIdx.x;
  if (i < n) {
    float w = W0[i];
    unsigned short h = f2bf_rne(w);
    h0[i] = h;
    l0[i] = f2bf_rne(w - bf2f(h));
    w = W1[i];
    h = f2bf_rne(w);
    h1[i] = h;
    l1[i] = f2bf_rne(w - bf2f(h));
  }
}

// Split x (n4 float4s) into hi/lo bf16 patterns, vectorized, grid-stride.
__global__ __launch_bounds__(256)
void xsplit(const float* __restrict__ x, unsigned short* __restrict__ xh,
            unsigned short* __restrict__ xl, int n4) {
  int i = blockIdx.x * 256 + threadIdx.x;
  const int stride = gridDim.x * 256;
  for (; i < n4; i += stride) {
    const float4 v = ((const float4*)x)[i];
    ushort4 hh, ll;
    hh.x = f2bf_rne(v.x); ll.x = f2bf_rne(v.x - bf2f(hh.x));
    hh.y = f2bf_rne(v.y); ll.y = f2bf_rne(v.y - bf2f(hh.y));
    hh.z = f2bf_rne(v.z); ll.z = f2bf_rne(v.z - bf2f(hh.z));
    hh.w = f2bf_rne(v.w); ll.w = f2bf_rne(v.w - bf2f(hh.w));
    ((ushort4*)xh)[i] = hh;
    ((ushort4*)xl)[i] = ll;
  }
}

// ---------------------------------------------------------------------------
// global -> LDS direct load, 16B/lane. LDS dest = wave-uniform base (HW adds
// lane*16). AS casts via integer roundtrip (CK amd_direct_load pattern).
// ---------------------------------------------------------------------------
typedef __attribute__((address_space(3))) unsigned int lds_u32;
typedef __attribute__((address_space(1))) unsigned int glb_u32;

__device__ __forceinline__ void gload_lds16(const void* g, void* l) {
  __builtin_amdgcn_global_load_lds(
      (glb_u32*)(unsigned long long)g,
      (lds_u32*)(unsigned int)(unsigned long long)l, 16, 0, 0);
}

// ---------------------------------------------------------------------------
// Unified MFMA GEMM (NT): C[r,n] = bias[n] + sum_k A(r,k)*W(n,k), K=N=512.
// NAT=1: A = A0 (spikes);   acc += A0.Bh + A0.Bl                    (2 MFMA)
// NAT=2: A = A0+A1 (xh,xl); acc += A0.Bh + A0.Bl + A1.Bh + A1.Bl   (4 MFMA)
// 128x128 tile, BK=32, 4 waves (2x2 of 64x64), 16x16x32 MFMA, 4x4 frags/wave,
// global_load_lds width-16 staging, 2-barrier K-loop (m97 structure).
//
// Bank-deconflict: LDS slot (row, c) holds global k-chunk c ^ ((row>>1)&3).
// Permutation lives in the per-lane global source address (LDS write stays
// linear for global_load_lds) and in the fragment-read slot index; 16 lanes
// of a b128 read then span 8 distinct bank-quads (2-way only = free).
// ---------------------------------------------------------------------------
template <int NAT>
__global__ __launch_bounds__(256)
void gemm_mfma(const unsigned short* __restrict__ A0,
               const unsigned short* __restrict__ A1,
               const unsigned short* __restrict__ Bhp,
               const unsigned short* __restrict__ Blp,
               const float* __restrict__ bias, float* __restrict__ C, int M) {
  constexpr int K = 512, N = 512;
  constexpr int NB = NAT + 2;               // LDS buffers
  __shared__ s16x8 sm[NB * 512];            // each buf: 128 rows x 32 bf16

  const int tid  = threadIdx.x;
  const int w    = tid >> 6;
  const int lane = tid & 63;
  const int wr   = w >> 1;     // wave row 0..1 (64 rows)
  const int wc   = w & 1;      // wave col 0..1
  const int frow = lane & 15;  // fragment row/col within 16x16
  const int kgrp = lane >> 4;  // k-group 0..3 (8 bf16 each)
  const int swzf = (frow >> 1) & 3;          // read-side permutation
  const int cslot = kgrp ^ swzf;             // LDS slot holding our k-chunk

  const int mtile = blockIdx.x * 128;
  const int ntile = blockIdx.y * 128;

  const unsigned short* srcs[NB];
  srcs[0] = A0;
  if (NAT == 2) srcs[1] = A1;
  srcs[NAT]     = Bhp;
  srcs[NAT + 1] = Blp;

  f32x4 acc[4][4];
#pragma unroll
  for (int i = 0; i < 4; ++i)
#pragma unroll
    for (int j = 0; j < 4; ++j) acc[i][j] = (f32x4){0.f, 0.f, 0.f, 0.f};

  for (int kt = 0; kt < K / 32; ++kt) {
    const int kbase = kt * 32;
    __syncthreads();  // previous fragment reads complete before overwrite
#pragma unroll
    for (int r = 0; r < 2; ++r) {
      const int chunk = r * 4 + w;          // 0..7, wave-uniform
      const int li    = chunk * 64 + lane;  // 16B unit 0..511
      const int row   = li >> 2;            // tile row 0..127
      const int c     = li & 3;             // LDS slot within row
      const int chg   = c ^ ((row >> 1) & 3);  // global k-chunk for this slot
      const int coff  = kbase + chg * 8;
#pragma unroll
      for (int buf = 0; buf < NB; ++buf) {
        const int rbase = (buf < NAT) ? mtile : ntile;
        gload_lds16(srcs[buf] + (size_t)(rbase + row) * K + coff,
                    &sm[buf * 512 + chunk * 64]);
      }
    }
    __syncthreads();  // vmcnt(0) drain -> LDS writes visible

    s16x8 a0f[4], a1f[4], bhf[4], blf[4];
#pragma unroll
    for (int mi = 0; mi < 4; ++mi) {
      const int off = (wr * 64 + mi * 16 + frow) * 4 + cslot;
      a0f[mi] = sm[off];
      if (NAT == 2) a1f[mi] = sm[512 + off];
    }
#pragma unroll
    for (int nj = 0; nj < 4; ++nj) {
      const int off = (wc * 64 + nj * 16 + frow) * 4 + cslot;
      bhf[nj] = sm[NAT * 512 + off];
      blf[nj] = sm[(NAT + 1) * 512 + off];
    }
#pragma unroll
    for (int mi = 0; mi < 4; ++mi)
#pragma unroll
      for (int nj = 0; nj < 4; ++nj) {
        acc[mi][nj] = __builtin_amdgcn_mfma_f32_16x16x32_bf16(
            a0f[mi], bhf[nj], acc[mi][nj], 0, 0, 0);
        acc[mi][nj] = __builtin_amdgcn_mfma_f32_16x16x32_bf16(
            a0f[mi], blf[nj], acc[mi][nj], 0, 0, 0);
        if (NAT == 2) {
          acc[mi][nj] = __builtin_amdgcn_mfma_f32_16x16x32_bf16(
              a1f[mi], bhf[nj], acc[mi][nj], 0, 0, 0);
          acc[mi][nj] = __builtin_amdgcn_mfma_f32_16x16x32_bf16(
              a1f[mi], blf[nj], acc[mi][nj], 0, 0, 0);
        }
      }
  }

  // epilogue: C/D layout col=lane&15, row=(lane>>4)*4+reg  [m89/m91]
#pragma unroll
  for (int nj = 0; nj < 4; ++nj) {
    const int col = ntile + wc * 64 + nj * 16 + frow;
    const float b = bias[col];
#pragma unroll
    for (int mi = 0; mi < 4; ++mi) {
#pragma unroll
      for (int ri = 0; ri < 4; ++ri) {
        const int row = mtile + wr * 64 + mi * 16 + kgrp * 4 + ri;
        C[(size_t)row * N + col] = acc[mi][nj][ri] + b;
      }
    }
  }
}

// ---------------------------------------------------------------------------
// Fallback GEMM1 (NT, fp32 vector), natural row order.
// ---------------------------------------------------------------------------
__global__ __launch_bounds__(256)
void gemm_nt(const float* __restrict__ A, const float* __restrict__ W,
             const float* __restrict__ bias, float* __restrict__ C,
             int M, int N, int K) {
  __shared__ float4 As[128 * 4];
  __shared__ float4 Bs[128 * 4];

  const int tid  = threadIdx.x;
  const int w    = tid >> 6;
  const int lane = tid & 63;
  const int m0 = (w >> 1) * 64 + (lane >> 3) * 8;
  const int n0 = (w & 1)  * 64 + (lane & 7) * 8;

  const int mtile = blockIdx.x * 128;
  const int ntile = blockIdx.y * 128;

  const int sr  = tid >> 1;
  const int sc  = (tid & 1) * 2;
  const int swz = (sr >> 3) & 3;

  const float4* ag = (const float4*)(A + (size_t)(mtile + sr) * K);
  const float4* bg = (const float4*)(W + (size_t)(ntile + sr) * K);

  float acc[8][8];
#pragma unroll
  for (int i = 0; i < 8; ++i)
#pragma unroll
    for (int j = 0; j < 8; ++j) acc[i][j] = 0.f;

  for (int k0 = 0; k0 < K; k0 += 16) {
    const int kc4 = k0 >> 2;
    float4 av0 = ag[kc4 + sc], av1 = ag[kc4 + sc + 1];
    float4 bv0 = bg[kc4 + sc], bv1 = bg[kc4 + sc + 1];
    __syncthreads();
    As[sr * 4 + (sc ^ swz)] = av0;  As[sr * 4 + ((sc + 1) ^ swz)] = av1;
    Bs[sr * 4 + (sc ^ swz)] = bv0;  Bs[sr * 4 + ((sc + 1) ^ swz)] = bv1;
    __syncthreads();

#pragma unroll
    for (int kc = 0; kc < 4; ++kc) {
      float4 a4[8], b4[8];
#pragma unroll
      for (int i = 0; i < 8; ++i) {
        const int m = m0 + i;
        a4[i] = As[m * 4 + (kc ^ ((m >> 3) & 3))];
        const int n = n0 + i;
        b4[i] = Bs[n * 4 + (kc ^ ((n >> 3) & 3))];
      }
#pragma unroll
      for (int i = 0; i < 8; ++i)
#pragma unroll
        for (int j = 0; j < 8; ++j) {
          acc[i][j] += a4[i].x * b4[j].x;
          acc[i][j] += a4[i].y * b4[j].y;
          acc[i][j] += a4[i].z * b4[j].z;
          acc[i][j] += a4[i].w * b4[j].w;
        }
    }
  }

  float bb[8];
#pragma unroll
  for (int j = 0; j < 8; ++j) bb[j] = bias[ntile + n0 + j];
#pragma unroll
  for (int i = 0; i < 8; ++i) {
    float* cp = C + (size_t)(mtile + m0 + i) * N + ntile + n0;
    float4 o0, o1;
    o0.x = acc[i][0] + bb[0]; o0.y = acc[i][1] + bb[1];
    o0.z = acc[i][2] + bb[2]; o0.w = acc[i][3] + bb[3];
    o1.x = acc[i][4] + bb[4]; o1.y = acc[i][5] + bb[5];
    o1.z = acc[i][6] + bb[6]; o1.w = acc[i][7] + bb[7];
    ((float4*)cp)[0] = o0;
    ((float4*)cp)[1] = o1;
  }
}

// ---------------------------------------------------------------------------
// LIF scan over T on [B,T,H] currents. Chain (b,h): stride H per step.
// Wave = 64 consecutive h -> 256B contiguous per timestep (coalesced).
// PF=64 prefetch ring: 16384 threads x 64 x 4B = 4MB in flight chip-wide;
// Little's law at ~900ns HBM latency -> ~4.5 TB/s (PF=32 measured ~2-3).
// ---------------------------------------------------------------------------
constexpr int PF = 64;  // divides Tsz

__global__ __launch_bounds__(64)
void lif_spikes_bf16(const float* __restrict__ iin,
                     unsigned short* __restrict__ sout) {
  const int idx = blockIdx.x * 64 + threadIdx.x;  // 0..B*H-1
  const int b = idx >> 9, h = idx & 511;
  const float* p = iin + (size_t)b * Tsz * Hsz + h;
  unsigned short* q = sout + (size_t)b * Tsz * Hsz + h;

  float buf[PF];
#pragma unroll
  for (int j = 0; j < PF; ++j) buf[j] = p[(size_t)j * Hsz];

  float u = 0.f, s = 0.f;
  int t = 0;
  for (; t < Tsz - PF; t += PF) {
#pragma unroll
    for (int j = 0; j < PF; ++j) {
      const float cur = buf[j];
      buf[j] = p[(size_t)(t + PF + j) * Hsz];  // prefetch next block
      u = DECAY * (u - s * THRESH) + cur;
      s = (u > THRESH) ? 1.f : 0.f;
      q[(size_t)(t + j) * Hsz] =
          (u > THRESH) ? (unsigned short)0x3F80 : (unsigned short)0;
    }
  }
#pragma unroll
  for (int j = 0; j < PF; ++j) {
    const float cur = buf[j];
    u = DECAY * (u - s * THRESH) + cur;
    s = (u > THRESH) ? 1.f : 0.f;
    q[(size_t)(t + j) * Hsz] =
        (u > THRESH) ? (unsigned short)0x3F80 : (unsigned short)0;
  }
}

__global__ __launch_bounds__(64)
void lif_last_f32(const float* __restrict__ iin, float* __restrict__ sout) {
  const int idx = blockIdx.x * 64 + threadIdx.x;
  const int b = idx >> 9, h = idx & 511;
  const float* p = iin + (size_t)b * Tsz * Hsz + h;

  float buf[PF];
#pragma unroll
  for (int j = 0; j < PF; ++j) buf[j] = p[(size_t)j * Hsz];

  float u = 0.f, s = 0.f;
  int t = 0;
  for (; t < Tsz - PF; t += PF) {
#pragma unroll
    for (int j = 0; j < PF; ++j) {
      const float cur = buf[j];
      buf[j] = p[(size_t)(t + PF + j) * Hsz];
      u = DECAY * (u - s * THRESH) + cur;
      s = (u > THRESH) ? 1.f : 0.f;
    }
  }
#pragma unroll
  for (int j = 0; j < PF; ++j) {
    const float cur = buf[j];
    u = DECAY * (u - s * THRESH) + cur;
    s = (u > THRESH) ? 1.f : 0.f;
  }
  sout[idx] = s;  // sl[b*H + h]
}

// ---------------------------------------------------------------------------
// FC: out[b,o] = fc_b[o] + sum_h sl[b,h] * fcW[o,h].
// ---------------------------------------------------------------------------
__global__ __launch_bounds__(256)
void fc_kernel(const float* __restrict__ sl, const float* __restrict__ fcW,
               const float* __restrict__ fcb, float* __restrict__ out) {
  const int b = blockIdx.x;
  const int o = threadIdx.x;
  const float4* wv = (const float4*)(fcW + (size_t)o * Hsz);
  const float4* sv = (const float4*)(sl + (size_t)b * Hsz);
  float acc = 0.f;
#pragma unroll 4
  for (int k = 0; k < Hsz / 4; ++k) {
    const float4 a = sv[k];
    const float4 ww = wv[k];
    acc += a.x * ww.x + a.y * ww.y + a.z * ww.z + a.w * ww.w;
  }
  out[(size_t)b * Osz + o] = acc + fcb[o];
}

// ---------------------------------------------------------------------------
extern "C" void kernel_launch(void* const* d_in, const int* in_sizes, int n_in,
                              void* d_out, int out_size, void* d_ws,
                              size_t ws_size, hipStream_t stream) {
  const float* x   = (const float*)d_in[0];  // [B,T,D]
  const float* W0  = (const float*)d_in[1];  // [H,D]
  const float* b0  = (const float*)d_in[2];  // [H]
  const float* W1  = (const float*)d_in[3];  // [H,H]
  const float* b1  = (const float*)d_in[4];  // [H]
  const float* fcW = (const float*)d_in[5];  // [O,H]
  const float* fcb = (const float*)d_in[6];  // [O]
  float* out = (float*)d_out;                // [B,O]

  constexpr size_t ELEMS = (size_t)Bsz * Tsz * Hsz;  // 16.7M (= B*T*D too)
  constexpr size_t WSZ   = (size_t)Hsz * Dsz;        // 262144

  // Layout: i0 | s0(=xh) | w1h | w1l | sl | xl | w0h | w0l
  float*          ws   = (float*)d_ws;
  float*          i0   = ws;                               // 64MB, reused as i1
  unsigned short* us0  = (unsigned short*)(ws + ELEMS);    // xh then s0, 32MB
  unsigned short* w1h  = us0 + ELEMS;
  unsigned short* w1l  = w1h + WSZ;
  float*          sl   = (float*)(w1l + WSZ);              // [B,H]
  unsigned short* uxl  = (unsigned short*)(sl + (size_t)Bsz * Hsz);  // 32MB
  unsigned short* w0h  = uxl + ELEMS;
  unsigned short* w0l  = w0h + WSZ;
  float*          i1   = i0;

  const size_t need_full =
      (char*)(w0l + WSZ) - (char*)d_ws;  // ~130MB
  const bool mfma1 = ws_size >= need_full;

  const int M = Bsz * Tsz;  // 32768
  dim3 gtile(M / 128, Hsz / 128);

  if (mfma1) {
    // Both weight splits in one launch (every call; no static state)
    wsplit2<<<(int)(WSZ / 256), 256, 0, stream>>>(W0, w0h, w0l, W1, w1h, w1l,
                                                  (int)WSZ);
    xsplit<<<2048, 256, 0, stream>>>(x, us0 /*xh*/, uxl, (int)(ELEMS / 4));
    // GEMM1 (MFMA 4-term): i0[r,h] = x[r,:].W0[h,:] + b0[h]
    gemm_mfma<2><<<gtile, 256, 0, stream>>>(us0, uxl, w0h, w0l, b0, i0, M);
  } else {
    wsplit2<<<(int)(WSZ / 256), 256, 0, stream>>>(W1, w1h, w1l, W1, w1h, w1l,
                                                  (int)WSZ);
    // Fallback: fp32 vector GEMM1
    gemm_nt<<<gtile, 256, 0, stream>>>(x, W0, b0, i0, M, Hsz, Dsz);
  }

  // LIF1: bf16 spike patterns for all t (overwrites xh region)
  lif_spikes_bf16<<<(Bsz * Hsz) / 64, 64, 0, stream>>>(i0, us0);

  // GEMM2 (MFMA 2-term): i1[r,g] = s0[r,:].W1[g,:] + b1[g]
  gemm_mfma<1><<<gtile, 256, 0, stream>>>(us0, nullptr, w1h, w1l, b1, i1, M);

  // LIF2: only final-timestep spikes
  lif_last_f32<<<(Bsz * Hsz) / 64, 64, 0, stream>>>(i1, sl);

  // FC
  fc_kernel<<<Bsz, Osz, 0, stream>>>(sl, fcW, fcb, out);
}

// Round 11
// 273.534 us; speedup vs baseline: 1.0779x; 1.0500x over previous
//
#include <hip/hip_runtime.h>

// SNN: x[B,T,D] -> GEMM1 -> LIF -> GEMM2 -> LIF -> (last t) -> FC -> out[B,O]
// B=32, T=1024, D=H=512, O=256. All intermediates in natural [B,T,H] order.
//
// Both GEMMs on bf16 MFMA via exact splits (R6/R8: PASS, absmax 0.0):
//   GEMM2: spikes {0,1} bf16-exact; W1 = w1h + w1l          -> 2 MFMAs/acc.
//   GEMM1: x = xh+xl, W0 = w0h+w0l; full 4-term product     -> 4 MFMAs/acc.
// R8: bank-deconflict verified (4.19M -> 0) but timing-null (2-phase loop is
// stage/barrier-bound). Reg-ring LIF ~null: spike stores share vmcnt with
// prefetch loads -> in-flight window collapses. LIF pair ~130us = target.
// R9/R10: producer/consumer LIF. Block = 4 waves / 64 chains; LDS double
// buffer of 64-t chunks. Waves 1-3 stage chunk k+1 via global_load_lds
// (6/5/5 instrs, 4 t-rows each); wave 0 is a PURE consumer (no vmem issues
// of its own -> no vmcnt stall before its ds_reads). One barrier per chunk.

#define DECAY 0.9f
#define THRESH 1.0f

constexpr int Bsz = 32;
constexpr int Tsz = 1024;
constexpr int Dsz = 512;
constexpr int Hsz = 512;
constexpr int Osz = 256;

using s16x8 = __attribute__((ext_vector_type(8))) short;
using f32x4 = __attribute__((ext_vector_type(4))) float;

// ---------------------------------------------------------------------------
// bf16 bit-pattern helpers (RNE)
// ---------------------------------------------------------------------------
__device__ __forceinline__ unsigned short f2bf_rne(float x) {
  unsigned b = __float_as_uint(x);
  return (unsigned short)((b + 0x7FFFu + ((b >> 16) & 1u)) >> 16);
}
__device__ __forceinline__ float bf2f(unsigned short h) {
  return __uint_as_float(((unsigned)h) << 16);
}

// Split BOTH weight matrices (each n fp32) into hi/lo bf16 patterns.
__global__ __launch_bounds__(256)
void wsplit2(const float* __restrict__ W0, unsigned short* __restrict__ h0,
             unsigned short* __restrict__ l0, const float* __restrict__ W1,
             unsigned short* __restrict__ h1, unsigned short* __restrict__ l1,
             int n) {
  const int i = blockIdx.x * 256 + threadIdx.x;
  if (i < n) {
    float w = W0[i];
    unsigned short h = f2bf_rne(w);
    h0[i] = h;
    l0[i] = f2bf_rne(w - bf2f(h));
    w = W1[i];
    h = f2bf_rne(w);
    h1[i] = h;
    l1[i] = f2bf_rne(w - bf2f(h));
  }
}

// Split x (n4 float4s) into hi/lo bf16 patterns, vectorized, grid-stride.
__global__ __launch_bounds__(256)
void xsplit(const float* __restrict__ x, unsigned short* __restrict__ xh,
            unsigned short* __restrict__ xl, int n4) {
  int i = blockIdx.x * 256 + threadIdx.x;
  const int stride = gridDim.x * 256;
  for (; i < n4; i += stride) {
    const float4 v = ((const float4*)x)[i];
    ushort4 hh, ll;
    hh.x = f2bf_rne(v.x); ll.x = f2bf_rne(v.x - bf2f(hh.x));
    hh.y = f2bf_rne(v.y); ll.y = f2bf_rne(v.y - bf2f(hh.y));
    hh.z = f2bf_rne(v.z); ll.z = f2bf_rne(v.z - bf2f(hh.z));
    hh.w = f2bf_rne(v.w); ll.w = f2bf_rne(v.w - bf2f(hh.w));
    ((ushort4*)xh)[i] = hh;
    ((ushort4*)xl)[i] = ll;
  }
}

// ---------------------------------------------------------------------------
// global -> LDS direct load, 16B/lane. LDS dest = wave-uniform base (HW adds
// lane*16). AS casts via integer roundtrip (CK amd_direct_load pattern).
// ---------------------------------------------------------------------------
typedef __attribute__((address_space(3))) unsigned int lds_u32;
typedef __attribute__((address_space(1))) unsigned int glb_u32;

__device__ __forceinline__ void gload_lds16(const void* g, void* l) {
  __builtin_amdgcn_global_load_lds(
      (glb_u32*)(unsigned long long)g,
      (lds_u32*)(unsigned int)(unsigned long long)l, 16, 0, 0);
}

// ---------------------------------------------------------------------------
// Unified MFMA GEMM (NT): C[r,n] = bias[n] + sum_k A(r,k)*W(n,k), K=N=512.
// NAT=1: A = A0 (spikes);   acc += A0.Bh + A0.Bl                    (2 MFMA)
// NAT=2: A = A0+A1 (xh,xl); acc += A0.Bh + A0.Bl + A1.Bh + A1.Bl   (4 MFMA)
// 128x128 tile, BK=32, 4 waves (2x2 of 64x64), 16x16x32 MFMA, 4x4 frags/wave,
// global_load_lds width-16 staging, 2-barrier K-loop (m97 structure).
// Bank-deconflict: LDS slot (row,c) holds global k-chunk c ^ ((row>>1)&3);
// verified 4.19M -> 0 conflicts (R8).
// ---------------------------------------------------------------------------
template <int NAT>
__global__ __launch_bounds__(256)
void gemm_mfma(const unsigned short* __restrict__ A0,
               const unsigned short* __restrict__ A1,
               const unsigned short* __restrict__ Bhp,
               const unsigned short* __restrict__ Blp,
               const float* __restrict__ bias, float* __restrict__ C, int M) {
  constexpr int K = 512, N = 512;
  constexpr int NB = NAT + 2;               // LDS buffers
  __shared__ s16x8 sm[NB * 512];            // each buf: 128 rows x 32 bf16

  const int tid  = threadIdx.x;
  const int w    = tid >> 6;
  const int lane = tid & 63;
  const int wr   = w >> 1;     // wave row 0..1 (64 rows)
  const int wc   = w & 1;      // wave col 0..1
  const int frow = lane & 15;  // fragment row/col within 16x16
  const int kgrp = lane >> 4;  // k-group 0..3 (8 bf16 each)
  const int swzf = (frow >> 1) & 3;          // read-side permutation
  const int cslot = kgrp ^ swzf;             // LDS slot holding our k-chunk

  const int mtile = blockIdx.x * 128;
  const int ntile = blockIdx.y * 128;

  const unsigned short* srcs[NB];
  srcs[0] = A0;
  if (NAT == 2) srcs[1] = A1;
  srcs[NAT]     = Bhp;
  srcs[NAT + 1] = Blp;

  f32x4 acc[4][4];
#pragma unroll
  for (int i = 0; i < 4; ++i)
#pragma unroll
    for (int j = 0; j < 4; ++j) acc[i][j] = (f32x4){0.f, 0.f, 0.f, 0.f};

  for (int kt = 0; kt < K / 32; ++kt) {
    const int kbase = kt * 32;
    __syncthreads();  // previous fragment reads complete before overwrite
#pragma unroll
    for (int r = 0; r < 2; ++r) {
      const int chunk = r * 4 + w;          // 0..7, wave-uniform
      const int li    = chunk * 64 + lane;  // 16B unit 0..511
      const int row   = li >> 2;            // tile row 0..127
      const int c     = li & 3;             // LDS slot within row
      const int chg   = c ^ ((row >> 1) & 3);  // global k-chunk for this slot
      const int coff  = kbase + chg * 8;
#pragma unroll
      for (int buf = 0; buf < NB; ++buf) {
        const int rbase = (buf < NAT) ? mtile : ntile;
        gload_lds16(srcs[buf] + (size_t)(rbase + row) * K + coff,
                    &sm[buf * 512 + chunk * 64]);
      }
    }
    __syncthreads();  // vmcnt(0) drain -> LDS writes visible

    s16x8 a0f[4], a1f[4], bhf[4], blf[4];
#pragma unroll
    for (int mi = 0; mi < 4; ++mi) {
      const int off = (wr * 64 + mi * 16 + frow) * 4 + cslot;
      a0f[mi] = sm[off];
      if (NAT == 2) a1f[mi] = sm[512 + off];
    }
#pragma unroll
    for (int nj = 0; nj < 4; ++nj) {
      const int off = (wc * 64 + nj * 16 + frow) * 4 + cslot;
      bhf[nj] = sm[NAT * 512 + off];
      blf[nj] = sm[(NAT + 1) * 512 + off];
    }
#pragma unroll
    for (int mi = 0; mi < 4; ++mi)
#pragma unroll
      for (int nj = 0; nj < 4; ++nj) {
        acc[mi][nj] = __builtin_amdgcn_mfma_f32_16x16x32_bf16(
            a0f[mi], bhf[nj], acc[mi][nj], 0, 0, 0);
        acc[mi][nj] = __builtin_amdgcn_mfma_f32_16x16x32_bf16(
            a0f[mi], blf[nj], acc[mi][nj], 0, 0, 0);
        if (NAT == 2) {
          acc[mi][nj] = __builtin_amdgcn_mfma_f32_16x16x32_bf16(
              a1f[mi], bhf[nj], acc[mi][nj], 0, 0, 0);
          acc[mi][nj] = __builtin_amdgcn_mfma_f32_16x16x32_bf16(
              a1f[mi], blf[nj], acc[mi][nj], 0, 0, 0);
        }
      }
  }

  // epilogue: C/D layout col=lane&15, row=(lane>>4)*4+reg  [m89/m91]
#pragma unroll
  for (int nj = 0; nj < 4; ++nj) {
    const int col = ntile + wc * 64 + nj * 16 + frow;
    const float b = bias[col];
#pragma unroll
    for (int mi = 0; mi < 4; ++mi) {
#pragma unroll
      for (int ri = 0; ri < 4; ++ri) {
        const int row = mtile + wr * 64 + mi * 16 + kgrp * 4 + ri;
        C[(size_t)row * N + col] = acc[mi][nj][ri] + b;
      }
    }
  }
}

// ---------------------------------------------------------------------------
// Fallback GEMM1 (NT, fp32 vector), natural row order.
// ---------------------------------------------------------------------------
__global__ __launch_bounds__(256)
void gemm_nt(const float* __restrict__ A, const float* __restrict__ W,
             const float* __restrict__ bias, float* __restrict__ C,
             int M, int N, int K) {
  __shared__ float4 As[128 * 4];
  __shared__ float4 Bs[128 * 4];

  const int tid  = threadIdx.x;
  const int w    = tid >> 6;
  const int lane = tid & 63;
  const int m0 = (w >> 1) * 64 + (lane >> 3) * 8;
  const int n0 = (w & 1)  * 64 + (lane & 7) * 8;

  const int mtile = blockIdx.x * 128;
  const int ntile = blockIdx.y * 128;

  const int sr  = tid >> 1;
  const int sc  = (tid & 1) * 2;
  const int swz = (sr >> 3) & 3;

  const float4* ag = (const float4*)(A + (size_t)(mtile + sr) * K);
  const float4* bg = (const float4*)(W + (size_t)(ntile + sr) * K);

  float acc[8][8];
#pragma unroll
  for (int i = 0; i < 8; ++i)
#pragma unroll
    for (int j = 0; j < 8; ++j) acc[i][j] = 0.f;

  for (int k0 = 0; k0 < K; k0 += 16) {
    const int kc4 = k0 >> 2;
    float4 av0 = ag[kc4 + sc], av1 = ag[kc4 + sc + 1];
    float4 bv0 = bg[kc4 + sc], bv1 = bg[kc4 + sc + 1];
    __syncthreads();
    As[sr * 4 + (sc ^ swz)] = av0;  As[sr * 4 + ((sc + 1) ^ swz)] = av1;
    Bs[sr * 4 + (sc ^ swz)] = bv0;  Bs[sr * 4 + ((sc + 1) ^ swz)] = bv1;
    __syncthreads();

#pragma unroll
    for (int kc = 0; kc < 4; ++kc) {
      float4 a4[8], b4[8];
#pragma unroll
      for (int i = 0; i < 8; ++i) {
        const int m = m0 + i;
        a4[i] = As[m * 4 + (kc ^ ((m >> 3) & 3))];
        const int n = n0 + i;
        b4[i] = Bs[n * 4 + (kc ^ ((n >> 3) & 3))];
      }
#pragma unroll
      for (int i = 0; i < 8; ++i)
#pragma unroll
        for (int j = 0; j < 8; ++j) {
          acc[i][j] += a4[i].x * b4[j].x;
          acc[i][j] += a4[i].y * b4[j].y;
          acc[i][j] += a4[i].z * b4[j].z;
          acc[i][j] += a4[i].w * b4[j].w;
        }
    }
  }

  float bb[8];
#pragma unroll
  for (int j = 0; j < 8; ++j) bb[j] = bias[ntile + n0 + j];
#pragma unroll
  for (int i = 0; i < 8; ++i) {
    float* cp = C + (size_t)(mtile + m0 + i) * N + ntile + n0;
    float4 o0, o1;
    o0.x = acc[i][0] + bb[0]; o0.y = acc[i][1] + bb[1];
    o0.z = acc[i][2] + bb[2]; o0.w = acc[i][3] + bb[3];
    o1.x = acc[i][4] + bb[4]; o1.y = acc[i][5] + bb[5];
    o1.z = acc[i][6] + bb[6]; o1.w = acc[i][7] + bb[7];
    ((float4*)cp)[0] = o0;
    ((float4*)cp)[1] = o1;
  }
}

// ---------------------------------------------------------------------------
// Producer/consumer LIF. Block = 256 thr (4 waves) owns 64 chains
// (one b, h0..h0+63). LDS double buffer of C=64-timestep chunks
// (2 x 64 x 64 floats = 32KB). Waves 1-3 stage chunk k+1 via global_load_lds
// (6/5/5 instrs; each instr = 4 t-rows: lane l -> row+(l>>4), col (l&15)*4);
// wave 0 is a pure consumer: serial recurrence on chunk k from LDS (lane l
// = chain h0+l; stride-64 rows -> 2-way bank = free). One __syncthreads per
// chunk; producers' vmcnt(0)-before-barrier overlaps consumer compute.
// STORE: write bf16 spike patterns per t; else only final spike to lastout.
// ---------------------------------------------------------------------------
template <bool STORE>
__global__ __launch_bounds__(256)
void lif_pc(const float* __restrict__ iin, unsigned short* __restrict__ sout,
            float* __restrict__ lastout) {
  constexpr int C = 64;
  constexpr int NC = Tsz / C;  // 16
  __shared__ float lds[2][C][64];

  const int tid  = threadIdx.x;
  const int w    = tid >> 6;
  const int lane = tid & 63;
  const int b    = blockIdx.x >> 3;
  const int h0   = (blockIdx.x & 7) * 64;

  const float* base = iin + (size_t)b * Tsz * Hsz + h0;

  // waves 1-3: row base / instr count (each gload_lds16 covers 4 t-rows)
  const int rb  = (w == 1) ? 0 : (w == 2) ? 24 : 44;
  const int cnt = (w == 1) ? 6 : 5;

  // stage chunk kk into buffer nb (producers only)
#define LIF_STAGE(kk, nb)                                                    \
  if (w != 0) {                                                              \
    for (int j = 0; j < cnt; ++j) {                                          \
      const int row = rb + j * 4;                                            \
      const float* g =                                                       \
          base + (size_t)((kk)*C + row + (lane >> 4)) * Hsz + (lane & 15) * 4;\
      gload_lds16(g, &lds[nb][row][0]);                                      \
    }                                                                        \
  }

  LIF_STAGE(0, 0);
  __syncthreads();  // producers' vmcnt(0) -> chunk 0 resident

  float u = 0.f, s = 0.f;
  unsigned short* q =
      STORE ? sout + (size_t)b * Tsz * Hsz + h0 + lane : (unsigned short*)0;

  for (int k = 0; k < NC; ++k) {
    if (k + 1 < NC) LIF_STAGE(k + 1, (k + 1) & 1);
    if (w == 0) {
      const int cb = k & 1;
#pragma unroll 16
      for (int t = 0; t < C; ++t) {
        const float cur = lds[cb][t][lane];
        u = DECAY * (u - s * THRESH) + cur;
        s = (u > THRESH) ? 1.f : 0.f;
        if (STORE)
          q[(size_t)(k * C + t) * Hsz] =
              (u > THRESH) ? (unsigned short)0x3F80 : (unsigned short)0;
      }
    }
    __syncthreads();  // buf (k+1)&1 resident; buf k&1 free for k+2 staging
  }
#undef LIF_STAGE

  if (!STORE && w == 0) lastout[(size_t)b * Hsz + h0 + lane] = s;
}

// ---------------------------------------------------------------------------
// FC: out[b,o] = fc_b[o] + sum_h sl[b,h] * fcW[o,h].
// ---------------------------------------------------------------------------
__global__ __launch_bounds__(256)
void fc_kernel(const float* __restrict__ sl, const float* __restrict__ fcW,
               const float* __restrict__ fcb, float* __restrict__ out) {
  const int b = blockIdx.x;
  const int o = threadIdx.x;
  const float4* wv = (const float4*)(fcW + (size_t)o * Hsz);
  const float4* sv = (const float4*)(sl + (size_t)b * Hsz);
  float acc = 0.f;
#pragma unroll 4
  for (int k = 0; k < Hsz / 4; ++k) {
    const float4 a = sv[k];
    const float4 ww = wv[k];
    acc += a.x * ww.x + a.y * ww.y + a.z * ww.z + a.w * ww.w;
  }
  out[(size_t)b * Osz + o] = acc + fcb[o];
}

// ---------------------------------------------------------------------------
extern "C" void kernel_launch(void* const* d_in, const int* in_sizes, int n_in,
                              void* d_out, int out_size, void* d_ws,
                              size_t ws_size, hipStream_t stream) {
  const float* x   = (const float*)d_in[0];  // [B,T,D]
  const float* W0  = (const float*)d_in[1];  // [H,D]
  const float* b0  = (const float*)d_in[2];  // [H]
  const float* W1  = (const float*)d_in[3];  // [H,H]
  const float* b1  = (const float*)d_in[4];  // [H]
  const float* fcW = (const float*)d_in[5];  // [O,H]
  const float* fcb = (const float*)d_in[6];  // [O]
  float* out = (float*)d_out;                // [B,O]

  constexpr size_t ELEMS = (size_t)Bsz * Tsz * Hsz;  // 16.7M (= B*T*D too)
  constexpr size_t WSZ   = (size_t)Hsz * Dsz;        // 262144

  // Layout: i0 | s0(=xh) | w1h | w1l | sl | xl | w0h | w0l
  float*          ws   = (float*)d_ws;
  float*          i0   = ws;                               // 64MB, reused as i1
  unsigned short* us0  = (unsigned short*)(ws + ELEMS);    // xh then s0, 32MB
  unsigned short* w1h  = us0 + ELEMS;
  unsigned short* w1l  = w1h + WSZ;
  float*          sl   = (float*)(w1l + WSZ);              // [B,H]
  unsigned short* uxl  = (unsigned short*)(sl + (size_t)Bsz * Hsz);  // 32MB
  unsigned short* w0h  = uxl + ELEMS;
  unsigned short* w0l  = w0h + WSZ;
  float*          i1   = i0;

  const size_t need_full =
      (char*)(w0l + WSZ) - (char*)d_ws;  // ~130MB
  const bool mfma1 = ws_size >= need_full;

  const int M = Bsz * Tsz;  // 32768
  dim3 gtile(M / 128, Hsz / 128);

  if (mfma1) {
    // Both weight splits in one launch (every call; no static state)
    wsplit2<<<(int)(WSZ / 256), 256, 0, stream>>>(W0, w0h, w0l, W1, w1h, w1l,
                                                  (int)WSZ);
    xsplit<<<2048, 256, 0, stream>>>(x, us0 /*xh*/, uxl, (int)(ELEMS / 4));
    // GEMM1 (MFMA 4-term): i0[r,h] = x[r,:].W0[h,:] + b0[h]
    gemm_mfma<2><<<gtile, 256, 0, stream>>>(us0, uxl, w0h, w0l, b0, i0, M);
  } else {
    wsplit2<<<(int)(WSZ / 256), 256, 0, stream>>>(W1, w1h, w1l, W1, w1h, w1l,
                                                  (int)WSZ);
    // Fallback: fp32 vector GEMM1
    gemm_nt<<<gtile, 256, 0, stream>>>(x, W0, b0, i0, M, Hsz, Dsz);
  }

  // LIF1: bf16 spike patterns for all t (overwrites xh region)
  lif_pc<true><<<Bsz * 8, 256, 0, stream>>>(i0, us0, nullptr);

  // GEMM2 (MFMA 2-term): i1[r,g] = s0[r,:].W1[g,:] + b1[g]
  gemm_mfma<1><<<gtile, 256, 0, stream>>>(us0, nullptr, w1h, w1l, b1, i1, M);

  // LIF2: only final-timestep spikes
  lif_pc<false><<<Bsz * 8, 256, 0, stream>>>(i1, nullptr, sl);

  // FC
  fc_kernel<<<Bsz, Osz, 0, stream>>>(sl, fcW, fcb, out);
}